// Round 9
// baseline (74.220 us; speedup 1.0000x reference)
//
#include <hip/hip_runtime.h>

// GraphConv2d (EdgeConv): out[b,o,n] = max_k relu( W·[x_n, x_m-x_n] + b )
// Factorized: U[b,n,o] = (W1-W2)·x_n + b ; V[b,m,o] = W2·x_m
//             out = relu(U + max_k V[m_k])   (relu monotone, U k-invariant)
// B=2, C=64, N=65536, K=16, OUT=64.
// k2: channel-QUARTER x batch = 8 gather groups, group = blockIdx%8 -> one
// group per XCD (round-robin dispatch heuristic). Per-XCD gather table =
// 65536 x 16ch x bf16 = 2.1 MB, resident in the 4 MB private L2 with
// headroom for streams. Correctness does not depend on the XCD mapping.

using u32 = unsigned int;
using u16 = unsigned short;
typedef short short8 __attribute__((ext_vector_type(8)));
typedef float f32x4 __attribute__((ext_vector_type(4)));
typedef int i32x4 __attribute__((ext_vector_type(4)));
typedef u32 u32x4 __attribute__((ext_vector_type(4)));

#define NN 65536

static __device__ __forceinline__ u16 bf16r(float a) {
  u32 u = __builtin_bit_cast(u32, a);
  return (u16)((u + 0x7fffu + ((u >> 16) & 1u)) >> 16);  // RNE
}
static __device__ __forceinline__ u32 pack_bf16(float a, float b) {
  return (u32)bf16r(a) | ((u32)bf16r(b) << 16);
}
static __device__ __forceinline__ float bflo(u32 x) {
  return __builtin_bit_cast(float, x << 16);
}
static __device__ __forceinline__ float bfhi(u32 x) {
  return __builtin_bit_cast(float, x & 0xffff0000u);
}

// ---- kernel 0: Wcat[128][64] bf16: rows 0..63 = (W1-W2), 64..127 = W2 ----
__global__ __launch_bounds__(256) void prep_w(const float* __restrict__ W,
                                              u32* __restrict__ Wcat) {
  int id = blockIdx.x * 256 + threadIdx.x;  // 0..4095 (grid=16)
  int o = id >> 5, c2 = id & 31;
  float f0, f1;
  if (o < 64) {
    f0 = W[o * 128 + 2 * c2]     - W[o * 128 + 64 + 2 * c2];
    f1 = W[o * 128 + 2 * c2 + 1] - W[o * 128 + 64 + 2 * c2 + 1];
  } else {
    int om = o - 64;
    f0 = W[om * 128 + 64 + 2 * c2];
    f1 = W[om * 128 + 64 + 2 * c2 + 1];
  }
  Wcat[id] = pack_bf16(f0, f1);
}

// ---- kernel 1: U,V (bf16, channel-quarter-split) via MFMA GEMM ----
// A = x tile [64 nodes][64 ch] bf16 ; B^T = Wcat [128 outs][64 ch] bf16
// U/V layout: region (q,b) q=chan quarter: [(q*2+b)*N + node] rows of 8 u32.
__global__ __launch_bounds__(256, 4) void k1(const float* __restrict__ x,
                                             const float* __restrict__ bias,
                                             const u32* __restrict__ Wcat,
                                             u32* __restrict__ Up,
                                             u32* __restrict__ Vp) {
  __shared__ __align__(16) char smem[26880];  // Wb(18432)+Xa(8448); reused: TR(17408)
  u32* Wb = (u32*)smem;            // [128][36] u32  (row = 72 bf16, padded)
  u32* Xa = (u32*)(smem + 18432);  // [64][33] u32   (row = 66 bf16, padded)

  int t = threadIdx.x;
  int l = t & 63;   // lane
  int w = t >> 6;   // wave 0..3
  int b = blockIdx.x >> 10;
  int n0 = (blockIdx.x & 1023) << 6;

  // stage Wcat -> LDS (padded rows, conflict-free b128 reads later)
#pragma unroll
  for (int i = 0; i < 16; ++i) {
    int id = i * 256 + t;  // o = id>>5, c2 = id&31
    Wb[(id >> 5) * 36 + (id & 31)] = Wcat[id];
  }
  // stage x tile -> LDS bf16 pairs: Xa[node][ch], coalesced 256B reads
#pragma unroll
  for (int r = 0; r < 8; ++r) {
    int c2 = r * 4 + w;
    size_t base = ((size_t)(b * 64 + 2 * c2)) * NN + n0 + l;
    Xa[l * 33 + c2] = pack_bf16(x[base], x[base + NN]);
  }
  __syncthreads();

  f32x4 acc[8];
#pragma unroll
  for (int f = 0; f < 8; ++f) acc[f] = {0.f, 0.f, 0.f, 0.f};

  // wave w owns nodes 16w..16w+15 (C rows), all 128 outs (8 col-frags)
#pragma unroll
  for (int kb = 0; kb < 2; ++kb) {  // K = 64 = 2 x 32
    int ar = (16 * w + (l & 15)) * 33 + kb * 16 + 4 * (l >> 4);
    i32x4 av = {(int)Xa[ar], (int)Xa[ar + 1], (int)Xa[ar + 2], (int)Xa[ar + 3]};
    short8 a = __builtin_bit_cast(short8, av);
#pragma unroll
    for (int f = 0; f < 8; ++f) {
      i32x4 bv = *(const i32x4*)(Wb + (16 * f + (l & 15)) * 36 + kb * 16 + 4 * (l >> 4));
      short8 bb = __builtin_bit_cast(short8, bv);
      acc[f] = __builtin_amdgcn_mfma_f32_16x16x32_bf16(a, bb, acc[f], 0, 0, 0);
    }
  }

  float bs[4];
#pragma unroll
  for (int f = 0; f < 4; ++f) bs[f] = bias[16 * f + (l & 15)];

  __syncthreads();  // all waves done with Wb/Xa before reuse
  u16* TR16 = (u16*)smem;  // [64 nodes][136 u16]  (U: 0..63 | V: 64..127, pad 8)
#pragma unroll
  for (int f = 0; f < 4; ++f) {
#pragma unroll
    for (int r = 0; r < 4; ++r) {
      int node = 16 * w + 4 * (l >> 4) + r;  // D row = (lane>>4)*4 + reg
      int o = 16 * f + (l & 15);             // D col = lane&15
      float uval = acc[f][r] + bs[f];        // Wcat rows 0..63 already (W1-W2)
      float vval = acc[f + 4][r];
      TR16[node * 136 + o] = bf16r(uval);
      TR16[node * 136 + 64 + o] = bf16r(vval);
    }
  }
  __syncthreads();

  // writeback in channel-quarter-split layout: 32B segments per region
  u32* TR32 = (u32*)smem;
  int o2 = t & 63;
#pragma unroll
  for (int i = 0; i < 16; ++i) {
    int n = i * 4 + w;
    u32 v = TR32[n * 68 + o2];
    size_t node = (size_t)(n0 + n);
    if (o2 < 32) {
      int q = o2 >> 3, c = o2 & 7;
      Up[(((size_t)q * 2 + b) * NN + node) * 8 + c] = v;
    } else {
      int o2v = o2 - 32;
      int q = o2v >> 3, c = o2v & 7;
      Vp[(((size_t)q * 2 + b) * NN + node) * 8 + c] = v;
    }
  }
}

// ---- kernel 2: gather + max + relu, one (quarter,batch) group per XCD ----
// group g = bx&7 = (q,b); tile = bx>>3 (512 tiles x 128 nodes).
// Gather: 2 lanes per node, 16B each -> 32B V row (one L2 access, L2-hot).
__global__ __launch_bounds__(256, 8) void k2(const int* __restrict__ eidx,
                                             const u32* __restrict__ Uh,
                                             const u32* __restrict__ Vh,
                                             float* __restrict__ out) {
  __shared__ __align__(16) int eixT[16 * 136];    // [e][node] idx, transposed
  __shared__ __align__(16) float tile[16 * 136];  // [o][node] padded

  int t = threadIdx.x;
  int bx = blockIdx.x;
  int g = bx & 7;          // XCD-pinned group
  int q = g >> 1;          // channel quarter
  int b = g & 1;           // batch
  int n0 = (bx >> 3) << 7; // 128-node tile

  // stage + transpose this tile's 2048 indices (nt: don't evict V from L2)
  {
    const i32x4* ep = (const i32x4*)(eidx + ((size_t)b * NN + n0) * 16);
    i32x4 v0 = __builtin_nontemporal_load(ep + t);
    i32x4 v1 = __builtin_nontemporal_load(ep + t + 256);
    int node = t >> 2, e0 = (t & 3) * 4;
    eixT[(e0 + 0) * 136 + node] = v0.x;
    eixT[(e0 + 1) * 136 + node] = v0.y;
    eixT[(e0 + 2) * 136 + node] = v0.z;
    eixT[(e0 + 3) * 136 + node] = v0.w;
    eixT[(e0 + 0) * 136 + 64 + node] = v1.x;
    eixT[(e0 + 1) * 136 + 64 + node] = v1.y;
    eixT[(e0 + 2) * 136 + 64 + node] = v1.z;
    eixT[(e0 + 3) * 136 + 64 + node] = v1.w;
  }
  __syncthreads();

  int node = t >> 1;  // 0..127
  int qq = t & 1;     // 16B half of the 32B quarter-row

  const u32* Vb = Vh + (((size_t)q * 2 + b) * NN) * 8 + qq * 4;
  float mx[8];
#pragma unroll
  for (int i = 0; i < 8; ++i) mx[i] = -3.0e38f;

#pragma unroll
  for (int e = 0; e < 16; ++e) {
    int id = eixT[e * 136 + node];  // broadcast across the 2-lane group
    u32x4 v = *(const u32x4*)(Vb + (size_t)id * 8);  // 32B row, L2-hot
    mx[0] = fmaxf(mx[0], bflo(v.x)); mx[1] = fmaxf(mx[1], bfhi(v.x));
    mx[2] = fmaxf(mx[2], bflo(v.y)); mx[3] = fmaxf(mx[3], bfhi(v.y));
    mx[4] = fmaxf(mx[4], bflo(v.z)); mx[5] = fmaxf(mx[5], bfhi(v.z));
    mx[6] = fmaxf(mx[6], bflo(v.w)); mx[7] = fmaxf(mx[7], bfhi(v.w));
  }

  u32x4 uv = __builtin_nontemporal_load(
      (const u32x4*)(Uh + (((size_t)q * 2 + b) * NN + n0 + node) * 8 + qq * 4));
  tile[(qq * 8 + 0) * 136 + node] = fmaxf(bflo(uv.x) + mx[0], 0.f);
  tile[(qq * 8 + 1) * 136 + node] = fmaxf(bfhi(uv.x) + mx[1], 0.f);
  tile[(qq * 8 + 2) * 136 + node] = fmaxf(bflo(uv.y) + mx[2], 0.f);
  tile[(qq * 8 + 3) * 136 + node] = fmaxf(bfhi(uv.y) + mx[3], 0.f);
  tile[(qq * 8 + 4) * 136 + node] = fmaxf(bflo(uv.z) + mx[4], 0.f);
  tile[(qq * 8 + 5) * 136 + node] = fmaxf(bfhi(uv.z) + mx[5], 0.f);
  tile[(qq * 8 + 6) * 136 + node] = fmaxf(bflo(uv.w) + mx[6], 0.f);
  tile[(qq * 8 + 7) * 136 + node] = fmaxf(bfhi(uv.w) + mx[7], 0.f);
  __syncthreads();

  // coalesced output: this group's 16 channels x 128 nodes
  int col = t & 127;
  int oh = t >> 7;  // 0..1
#pragma unroll
  for (int r = 0; r < 8; ++r) {
    int o = r * 2 + oh;
    __builtin_nontemporal_store(
        tile[o * 136 + col],
        out + ((size_t)(b * 64 + q * 16 + o)) * NN + n0 + col);
  }
}

extern "C" void kernel_launch(void* const* d_in, const int* in_sizes, int n_in,
                              void* d_out, int out_size, void* d_ws, size_t ws_size,
                              hipStream_t stream) {
  const float* x = (const float*)d_in[0];
  const int* eidx = (const int*)d_in[1];
  const float* W = (const float*)d_in[2];
  const float* bias = (const float*)d_in[3];

  // ws: U (16 MB, 8 regions x N x 8 u32) | V (16 MB) | Wcat bf16 (16 KB)
  u32* Up = (u32*)d_ws;
  u32* Vp = Up + (size_t)8 * NN * 8;
  u32* Wcat = (u32*)((char*)d_ws + (size_t)32 * 1024 * 1024);

  prep_w<<<16, 256, 0, stream>>>(W, Wcat);
  k1<<<2 * 1024, 256, 0, stream>>>(x, bias, Wcat, Up, Vp);
  k2<<<4 * 1024, 256, 0, stream>>>(eidx, Up, Vp, (float*)d_out);
}

// Round 10
// 56.816 us; speedup vs baseline: 1.3063x; 1.3063x over previous
//
#include <hip/hip_runtime.h>

// GraphConv2d (EdgeConv): out[b,o,n] = max_k relu( W·[x_n, x_m-x_n] + b )
// Factorized: U[b,n,o] = (W1-W2)·x_n + b ; V[b,m,o] = W2·x_m
//             out = relu(U + max_k V[m_k])   (relu monotone, U k-invariant)
// B=2, C=64, N=65536, K=16, OUT=64.
// k2: channel-HALF x batch = 4 gather groups on XCD pairs (blockIdx%8
// round-robin heuristic): per-XCD table 4 MB (= L2), 64B rows -> minimum
// line-touches (4M). r9 ablation showed 32B rows / 8 groups doubles
// line-touches and loses 20us despite perfect residency.

using u32 = unsigned int;
using u16 = unsigned short;
typedef short short8 __attribute__((ext_vector_type(8)));
typedef float f32x4 __attribute__((ext_vector_type(4)));
typedef int i32x4 __attribute__((ext_vector_type(4)));
typedef u32 u32x4 __attribute__((ext_vector_type(4)));

#define NN 65536

static __device__ __forceinline__ u16 bf16r(float a) {
  u32 u = __builtin_bit_cast(u32, a);
  return (u16)((u + 0x7fffu + ((u >> 16) & 1u)) >> 16);  // RNE
}
static __device__ __forceinline__ u32 pack_bf16(float a, float b) {
  return (u32)bf16r(a) | ((u32)bf16r(b) << 16);
}
static __device__ __forceinline__ float bflo(u32 x) {
  return __builtin_bit_cast(float, x << 16);
}
static __device__ __forceinline__ float bfhi(u32 x) {
  return __builtin_bit_cast(float, x & 0xffff0000u);
}

// ---- kernel 0: Wcat[128][64] bf16: rows 0..63 = (W1-W2), 64..127 = W2 ----
__global__ __launch_bounds__(256) void prep_w(const float* __restrict__ W,
                                              u32* __restrict__ Wcat) {
  int id = blockIdx.x * 256 + threadIdx.x;  // 0..4095 (grid=16)
  int o = id >> 5, c2 = id & 31;
  float f0, f1;
  if (o < 64) {
    f0 = W[o * 128 + 2 * c2]     - W[o * 128 + 64 + 2 * c2];
    f1 = W[o * 128 + 2 * c2 + 1] - W[o * 128 + 64 + 2 * c2 + 1];
  } else {
    int om = o - 64;
    f0 = W[om * 128 + 64 + 2 * c2];
    f1 = W[om * 128 + 64 + 2 * c2 + 1];
  }
  Wcat[id] = pack_bf16(f0, f1);
}

// ---- kernel 1: U,V (bf16, channel-half-split) via MFMA GEMM C[64n x 128o] ----
// A-frags loaded DIRECTLY from global x (coalesced 64B/line per 16-lane row
// group, in-register f32->bf16 pack) -> no Xa LDS stage, 18.4KB LDS,
// 6 blocks/CU (was 4). B^T = Wcat [128 outs][64 ch] bf16 staged in LDS.
__global__ __launch_bounds__(256, 6) void k1(const float* __restrict__ x,
                                             const float* __restrict__ bias,
                                             const u32* __restrict__ Wcat,
                                             u32* __restrict__ Up,
                                             u32* __restrict__ Vp) {
  __shared__ __align__(16) char smem[18432];  // Wb [128][36] u32; reused: TR
  u32* Wb = (u32*)smem;

  int t = threadIdx.x;
  int l = t & 63;   // lane
  int w = t >> 6;   // wave 0..3
  int b = blockIdx.x >> 10;
  int n0 = (blockIdx.x & 1023) << 6;

  // stage Wcat -> LDS (padded rows, conflict-free b128 reads later)
#pragma unroll
  for (int i = 0; i < 16; ++i) {
    int id = i * 256 + t;  // o = id>>5, c2 = id&31
    Wb[(id >> 5) * 36 + (id & 31)] = Wcat[id];
  }
  __syncthreads();

  int row = 16 * w + (l & 15);  // C row (node) owned by this lane
  int kq = l >> 4;              // k-quarter 0..3
  const float* xb = x + (size_t)(b * 64) * NN + n0 + row;

  f32x4 acc[8];
#pragma unroll
  for (int f = 0; f < 8; ++f) acc[f] = {0.f, 0.f, 0.f, 0.f};

#pragma unroll
  for (int kb = 0; kb < 2; ++kb) {  // K = 64 = 2 x 32
    // A-frag: elem j <-> ch = kb*32 + 8*kq + j  (16x16x32 A: row=l&15, k=(l>>4)*8+j)
    int ch0 = kb * 32 + 8 * kq;
    u32 ap[4];
#pragma unroll
    for (int p = 0; p < 4; ++p) {
      float f0 = xb[(size_t)(ch0 + 2 * p) * NN];
      float f1 = xb[(size_t)(ch0 + 2 * p + 1) * NN];
      ap[p] = pack_bf16(f0, f1);
    }
    i32x4 av = {(int)ap[0], (int)ap[1], (int)ap[2], (int)ap[3]};
    short8 a = __builtin_bit_cast(short8, av);
#pragma unroll
    for (int f = 0; f < 8; ++f) {
      i32x4 bv = *(const i32x4*)(Wb + (16 * f + (l & 15)) * 36 + kb * 16 + 4 * kq);
      short8 bb = __builtin_bit_cast(short8, bv);
      acc[f] = __builtin_amdgcn_mfma_f32_16x16x32_bf16(a, bb, acc[f], 0, 0, 0);
    }
  }

  float bs[4];
#pragma unroll
  for (int f = 0; f < 4; ++f) bs[f] = bias[16 * f + (l & 15)];

  __syncthreads();  // all waves done reading Wb before TR reuse
  u16* TR16 = (u16*)smem;  // [64 nodes][136 u16] (U: 0..63 | V: 64..127, pad 8)
#pragma unroll
  for (int f = 0; f < 4; ++f) {
#pragma unroll
    for (int r = 0; r < 4; ++r) {
      int node = 16 * w + 4 * (l >> 4) + r;  // D row = (lane>>4)*4 + reg
      int o = 16 * f + (l & 15);             // D col = lane&15
      float uval = acc[f][r] + bs[f];        // Wcat rows 0..63 already (W1-W2)
      float vval = acc[f + 4][r];
      TR16[node * 136 + o] = bf16r(uval);
      TR16[node * 136 + 64 + o] = bf16r(vval);
    }
  }
  __syncthreads();

  // writeback in channel-half-split layout: per wave 4x 64B segments
  u32* TR32 = (u32*)smem;
  int o2 = t & 63;
#pragma unroll
  for (int i = 0; i < 16; ++i) {
    int n = i * 4 + w;
    u32 v = TR32[n * 68 + o2];
    size_t node = (size_t)(n0 + n);
    if (o2 < 32) {
      int hh = o2 >> 4, c = o2 & 15;
      Up[(((size_t)hh * 2 + b) * NN + node) * 16 + c] = v;
    } else {
      int o2v = o2 - 32;
      int hh = o2v >> 4, c = o2v & 15;
      Vp[(((size_t)hh * 2 + b) * NN + node) * 16 + c] = v;
    }
  }
}

// ---- kernel 2: gather + max + relu, XCD-pinned channel-half groups ----
// xcd = bx&7; group g = xcd>>1 = (hh,b); tile = (bx>>3)|((xcd&1)<<9).
// 4 lanes/node x 16B = 64B V row = 1 line per edge-visit (minimum touches).
// Explicit 8-deep load batches keep 8 line-requests in flight per lane.
__global__ __launch_bounds__(256, 8) void k2(const int* __restrict__ eidx,
                                             const u32* __restrict__ Uh,
                                             const u32* __restrict__ Vh,
                                             float* __restrict__ out) {
  __shared__ __align__(16) int eixT[16 * 65];    // [e][node] idx, transposed
  __shared__ __align__(16) float tile[32 * 65];  // [o][node] padded

  int t = threadIdx.x;
  int bx = blockIdx.x;
  int xcd = bx & 7;
  int g = xcd >> 1;        // 0..3
  int hh = g >> 1;         // channel half
  int b = g & 1;           // batch
  int n0 = ((bx >> 3) | ((xcd & 1) << 9)) << 6;

  // stage + transpose this tile's 1024 indices (nt: don't evict V from L2)
  {
    i32x4 v = __builtin_nontemporal_load(
        (const i32x4*)(eidx + ((size_t)b * NN + n0) * 16) + t);
    int node = t >> 2, e0 = (t & 3) * 4;
    eixT[(e0 + 0) * 65 + node] = v.x;
    eixT[(e0 + 1) * 65 + node] = v.y;
    eixT[(e0 + 2) * 65 + node] = v.z;
    eixT[(e0 + 3) * 65 + node] = v.w;
  }
  __syncthreads();

  int l = t & 63, w = t >> 6;
  int node = w * 16 + (l >> 2);  // 4 lanes per node
  int qq = l & 3;                // 16B quarter of the 64B half-row

  const u32* Vb = Vh + (((size_t)hh * 2 + b) * NN) * 16 + qq * 4;
  float mx[8];
#pragma unroll
  for (int i = 0; i < 8; ++i) mx[i] = -3.0e38f;

#pragma unroll
  for (int hb = 0; hb < 2; ++hb) {
    u32x4 vr[8];
#pragma unroll
    for (int e = 0; e < 8; ++e) {
      int id = eixT[(hb * 8 + e) * 65 + node];  // LDS broadcast (4-lane group)
      vr[e] = *(const u32x4*)(Vb + (size_t)id * 16);  // 64B row, 1 line
    }
#pragma unroll
    for (int e = 0; e < 8; ++e) {
      u32x4 v = vr[e];
      mx[0] = fmaxf(mx[0], bflo(v.x)); mx[1] = fmaxf(mx[1], bfhi(v.x));
      mx[2] = fmaxf(mx[2], bflo(v.y)); mx[3] = fmaxf(mx[3], bfhi(v.y));
      mx[4] = fmaxf(mx[4], bflo(v.z)); mx[5] = fmaxf(mx[5], bfhi(v.z));
      mx[6] = fmaxf(mx[6], bflo(v.w)); mx[7] = fmaxf(mx[7], bfhi(v.w));
    }
  }

  u32x4 uv = __builtin_nontemporal_load(
      (const u32x4*)(Uh + (((size_t)hh * 2 + b) * NN + n0 + node) * 16 + qq * 4));
  tile[(qq * 8 + 0) * 65 + node] = fmaxf(bflo(uv.x) + mx[0], 0.f);
  tile[(qq * 8 + 1) * 65 + node] = fmaxf(bfhi(uv.x) + mx[1], 0.f);
  tile[(qq * 8 + 2) * 65 + node] = fmaxf(bflo(uv.y) + mx[2], 0.f);
  tile[(qq * 8 + 3) * 65 + node] = fmaxf(bfhi(uv.y) + mx[3], 0.f);
  tile[(qq * 8 + 4) * 65 + node] = fmaxf(bflo(uv.z) + mx[4], 0.f);
  tile[(qq * 8 + 5) * 65 + node] = fmaxf(bfhi(uv.z) + mx[5], 0.f);
  tile[(qq * 8 + 6) * 65 + node] = fmaxf(bflo(uv.w) + mx[6], 0.f);
  tile[(qq * 8 + 7) * 65 + node] = fmaxf(bfhi(uv.w) + mx[7], 0.f);
  __syncthreads();

  // coalesced output: this group's 32 channels
#pragma unroll
  for (int r = 0; r < 8; ++r) {
    int o = r * 4 + (t >> 6);
    int col = t & 63;
    __builtin_nontemporal_store(
        tile[o * 65 + col],
        out + ((size_t)(b * 64 + hh * 32 + o)) * NN + n0 + col);
  }
}

extern "C" void kernel_launch(void* const* d_in, const int* in_sizes, int n_in,
                              void* d_out, int out_size, void* d_ws, size_t ws_size,
                              hipStream_t stream) {
  const float* x = (const float*)d_in[0];
  const int* eidx = (const int*)d_in[1];
  const float* W = (const float*)d_in[2];
  const float* bias = (const float*)d_in[3];

  // ws: U (16 MB, 4 regions x N x 16 u32) | V (16 MB) | Wcat bf16 (16 KB)
  u32* Up = (u32*)d_ws;
  u32* Vp = Up + (size_t)4 * NN * 16;
  u32* Wcat = (u32*)((char*)d_ws + (size_t)32 * 1024 * 1024);

  prep_w<<<16, 256, 0, stream>>>(W, Wcat);
  k1<<<2 * 1024, 256, 0, stream>>>(x, bias, Wcat, Up, Vp);
  k2<<<4 * 1024, 256, 0, stream>>>(eidx, Up, Vp, (float*)d_out);
}